// Round 11
// baseline (253.127 us; speedup 1.0000x reference)
//
#include <hip/hip_runtime.h>

#define DEV __device__ __forceinline__

// Truncated level-3 signature state: s1[4], s2[16] (i*4+j), s3[64] (i*16+j*4+k).

// Async global->LDS, 16B per lane. LDS dest is wave-uniform base + lane*16.
DEV void async_stage16(const void* gsrc, void* ldst) {
    __builtin_amdgcn_global_load_lds(
        (const __attribute__((address_space(1))) unsigned int*)gsrc,
        (__attribute__((address_space(3))) unsigned int*)ldst, 16, 0, 0);
}

// s <- s (x) exp(dx). ~112 VALU ops (factored):
//   h_j = dx_j/2; u_i = s1_i + dx_i/3; g_i = s1_i + h_i
//   t_ij = s2_ij + u_i*h_j (old s2);  s3[ijk] += t_ij*dx_k
//   s2[ij] += g_i*dx_j;  s1 += dx
DEV void sig_step(float s1[4], float s2[16], float s3[64], const float dx[4]) {
    float h[4], u[4], g[4];
#pragma unroll
    for (int j = 0; j < 4; ++j) {
        h[j] = 0.5f * dx[j];
        u[j] = fmaf(dx[j], (1.0f / 3.0f), s1[j]);
        g[j] = s1[j] + h[j];
    }
#pragma unroll
    for (int i = 0; i < 4; ++i)
#pragma unroll
        for (int j = 0; j < 4; ++j) {
            float t = fmaf(u[i], h[j], s2[i * 4 + j]);
#pragma unroll
            for (int k = 0; k < 4; ++k)
                s3[i * 16 + j * 4 + k] = fmaf(t, dx[k], s3[i * 16 + j * 4 + k]);
        }
#pragma unroll
    for (int i = 0; i < 4; ++i)
#pragma unroll
        for (int j = 0; j < 4; ++j)
            s2[i * 4 + j] = fmaf(g[i], dx[j], s2[i * 4 + j]);
#pragma unroll
    for (int i = 0; i < 4; ++i) s1[i] += dx[i];
}

// s = exp(dx)
DEV void sig_init(float s1[4], float s2[16], float s3[64], const float dx[4]) {
#pragma unroll
    for (int i = 0; i < 4; ++i) s1[i] = dx[i];
#pragma unroll
    for (int j = 0; j < 4; ++j) {
        float hj = 0.5f * dx[j];
#pragma unroll
        for (int k = 0; k < 4; ++k) s2[j * 4 + k] = hj * dx[k];
    }
#pragma unroll
    for (int i = 0; i < 4; ++i) {
        float ti = dx[i] * (1.0f / 3.0f);
#pragma unroll
        for (int jk = 0; jk < 16; ++jk) s3[i * 16 + jk] = ti * s2[jk];
    }
}

// a <- a (x) b, b read with stride 64 floats/term (LDS or global).
DEV void chen_fold(float a1[4], float a2[16], float a3[64], const float* __restrict__ b) {
    float b1[4], b2[16];
#pragma unroll
    for (int k = 0; k < 4; ++k) b1[k] = b[k * 64];
#pragma unroll
    for (int t = 0; t < 16; ++t) b2[t] = b[(4 + t) * 64];
#pragma unroll
    for (int i = 0; i < 4; ++i)
#pragma unroll
        for (int j = 0; j < 4; ++j)
#pragma unroll
            for (int k = 0; k < 4; ++k) {
                float v = a3[i * 16 + j * 4 + k] + b[(20 + i * 16 + j * 4 + k) * 64];
                v = fmaf(a2[i * 4 + j], b1[k], v);
                v = fmaf(a1[i], b2[j * 4 + k], v);
                a3[i * 16 + j * 4 + k] = v;
            }
#pragma unroll
    for (int i = 0; i < 4; ++i)
#pragma unroll
        for (int j = 0; j < 4; ++j)
            a2[i * 4 + j] = fmaf(a1[i], b1[j], a2[i * 4 + j] + b2[i * 4 + j]);
#pragma unroll
    for (int i = 0; i < 4; ++i) a1[i] += b1[i];
}

DEV void store_sig(float* dst, const float s1[4], const float s2[16], const float s3[64]) {
#pragma unroll
    for (int t = 0; t < 4; ++t) dst[t * 64] = s1[t];
#pragma unroll
    for (int t = 0; t < 16; ++t) dst[(4 + t) * 64] = s2[t];
#pragma unroll
    for (int t = 0; t < 64; ++t) dst[(20 + t) * 64] = s3[t];
}

DEV void load_sig(const float* src, float s1[4], float s2[16], float s3[64]) {
#pragma unroll
    for (int t = 0; t < 4; ++t) s1[t] = src[t * 64];
#pragma unroll
    for (int t = 0; t < 16; ++t) s2[t] = src[(4 + t) * 64];
#pragma unroll
    for (int t = 0; t < 64; ++t) s3[t] = src[(20 + t) * 64];
}

// float4-packed output write (84 floats = 21 float4, 16B-aligned).
DEV void write_out4(float* ob, const float s1[4], const float s2[16], const float s3[64]) {
    float4* o4 = reinterpret_cast<float4*>(ob);
    o4[0] = make_float4(s1[0], s1[1], s1[2], s1[3]);
#pragma unroll
    for (int t = 0; t < 4; ++t)
        o4[1 + t] = make_float4(s2[4 * t], s2[4 * t + 1], s2[4 * t + 2], s2[4 * t + 3]);
#pragma unroll
    for (int t = 0; t < 16; ++t)
        o4[5 + t] = make_float4(s3[4 * t], s3[4 * t + 1], s3[4 * t + 2], s3[4 * t + 3]);
}

// Geometry: B=64, T=1024, E=64, D=4.
// FUSED single-dispatch pipeline. Block (b,h): stage 64 frames to LDS
// (per-wave async), scan 4x16 increments, in-LDS fold -> half signature ->
// hsig/bdxh in ws. Then fence + atomicAdd(cnt[b]); the LAST of the 16 blocks
// for b performs the whole dyadic tree (pieces pg7-14, quarters pg3-6,
// pg1, pg2, pg0) reading hsig/bdxh (device-visible via fence/atomic).
__global__ __launch_bounds__(256, 2)
void fused_kernel(const float* __restrict__ x, float* __restrict__ hsig,
                  float* __restrict__ bdxh, unsigned int* __restrict__ cnt,
                  float* __restrict__ out) {
    __shared__ float lds[16384];          // 64 KiB: frames, later 3 sig slots
    __shared__ unsigned int last_flag;
    float4* lf = reinterpret_cast<float4*>(lds);       // lf[f*64 + e]
    const int b = blockIdx.x >> 4;
    const int h = blockIdx.x & 15;
    const int w = threadIdx.x >> 6;
    const int e = threadIdx.x & 63;
    const float4* xg4 = reinterpret_cast<const float4*>(x) + (long)b * 65536;
    const int fbase = h * 64;

    // ---- Phase 1: per-wave async stage (17 frames; w3: 16) ----
#pragma unroll
    for (int k = 0; k < 17; ++k) {
        if (k < 16 || w < 3) {
            const int f = w * 16 + k;
            async_stage16(xg4 + (long)(fbase + f) * 64 + e, &lf[f * 64]);
        }
    }
    if (w == 0 && h > 0) {     // half boundary increment export
        float4 pm = xg4[(long)(fbase - 1) * 64 + e];
        float4 p0 = xg4[(long)fbase * 64 + e];
        float* bb = &bdxh[(((long)(b * 16 + h)) * 4) * 64 + e];
        bb[0]   = p0.x - pm.x;
        bb[64]  = p0.y - pm.y;
        bb[128] = p0.z - pm.z;
        bb[192] = p0.w - pm.w;
    }
    asm volatile("s_waitcnt vmcnt(0)" ::: "memory");

    // ---- Phase 2: scan own chunk from LDS ----
    const int base = w * 16;
    const int NI = (w < 3) ? 16 : 15;
    float s1[4], s2[16], s3[64];
    float dxx[4];
#define DX_(a, c) { dxx[0] = c.x - a.x; dxx[1] = c.y - a.y; \
                    dxx[2] = c.z - a.z; dxx[3] = c.w - a.w; }
    float4 a = lf[base * 64 + e];
    float4 nx = lf[(base + 1) * 64 + e];
    DX_(a, nx); sig_init(s1, s2, s3, dxx);
    a = nx;
    nx = lf[(base + 2) * 64 + e];
#pragma unroll 1
    for (int j = 2; j <= NI; ++j) {
        float4 cu = nx;
        int jn = j + 1; jn = jn > NI ? NI : jn;
        nx = lf[(base + jn) * 64 + e];
        DX_(a, cu); sig_step(s1, s2, s3, dxx);
        a = cu;
    }
#undef DX_
    __syncthreads();                      // frames dead

    // ---- Phase 3: in-LDS fold -> half signature (wave 0) ----
    float* slotA = &lds[0];
    float* slotB = &lds[84 * 64];
    float* slotC = &lds[2 * 84 * 64];
    if (w == 1) store_sig(slotA + e, s1, s2, s3);
    if (w == 3) store_sig(slotB + e, s1, s2, s3);
    __syncthreads();
    if (w == 0) chen_fold(s1, s2, s3, slotA + e);
    if (w == 2) chen_fold(s1, s2, s3, slotB + e);
    __syncthreads();
    if (w == 2) store_sig(slotA + e, s1, s2, s3);
    __syncthreads();
    if (w == 0) {
        chen_fold(s1, s2, s3, slotA + e);
        store_sig(&hsig[(((long)(b * 16 + h)) * 84) * 64 + e], s1, s2, s3);
    }

    // ---- Arrive: release writes, count; last block of b runs the tree ----
    __threadfence();                      // release hsig/bdxh (device scope)
    __syncthreads();
    if (threadIdx.x == 0) {
        unsigned int old = atomicAdd(&cnt[b], 1u);
        last_flag = (old == 15u) ? 1u : 0u;
    }
    __syncthreads();
    if (!last_flag) return;
    __threadfence();                      // acquire other blocks' writes

    // ---- Tree phase (one block per b) ----
    const float* HS = hsig + (long)b * 16 * 84 * 64;
    const float* BD = bdxh + (long)b * 16 * 4 * 64;
    float* const ob = out + ((long)(b * 64 + e)) * 15 * 84;
#define BDX(hh) { const float* bb = BD + (long)(hh) * 4 * 64 + e; \
                  dxl[0] = bb[0]; dxl[1] = bb[64]; dxl[2] = bb[128]; dxl[3] = bb[192]; }
    float dxl[4];
    float t1[4], t2[16], t3[64];
    // r0: wave w -> piece w (halves 2w, 2w+1) -> pg 7+w
    load_sig(HS + (long)(2 * w) * 84 * 64 + e, t1, t2, t3);
    BDX(2 * w + 1); sig_step(t1, t2, t3, dxl);
    chen_fold(t1, t2, t3, HS + (long)(2 * w + 1) * 84 * 64 + e);
    write_out4(ob + (7 + w) * 84, t1, t2, t3);
    if (w == 1) store_sig(slotB + e, t1, t2, t3);
    if (w == 3) store_sig(slotC + e, t1, t2, t3);
    __syncthreads();
    // quarters q0 (w0), q1 (w2)
    if (w == 0) { BDX(2); sig_step(t1, t2, t3, dxl); chen_fold(t1, t2, t3, slotB + e);
                  write_out4(ob + 3 * 84, t1, t2, t3); }
    if (w == 2) { BDX(6); sig_step(t1, t2, t3, dxl); chen_fold(t1, t2, t3, slotC + e);
                  write_out4(ob + 4 * 84, t1, t2, t3); }
    __syncthreads();
    if (w == 2) store_sig(slotB + e, t1, t2, t3);   // q1
    __syncthreads();
    // pg1 = q0 (x) exp(bdx h=4) (x) q1  -> stash to slotA
    if (w == 0) { BDX(4); sig_step(t1, t2, t3, dxl); chen_fold(t1, t2, t3, slotB + e);
                  write_out4(ob + 1 * 84, t1, t2, t3); store_sig(slotA + e, t1, t2, t3); }
    __syncthreads();
    // r1: wave w -> piece 4+w (halves 8+2w, 9+2w) -> pg 11+w
    load_sig(HS + (long)(8 + 2 * w) * 84 * 64 + e, t1, t2, t3);
    BDX(9 + 2 * w); sig_step(t1, t2, t3, dxl);
    chen_fold(t1, t2, t3, HS + (long)(9 + 2 * w) * 84 * 64 + e);
    write_out4(ob + (11 + w) * 84, t1, t2, t3);
    if (w == 1) store_sig(slotB + e, t1, t2, t3);
    if (w == 3) store_sig(slotC + e, t1, t2, t3);
    __syncthreads();
    // quarters q2 (w0), q3 (w2)
    if (w == 0) { BDX(10); sig_step(t1, t2, t3, dxl); chen_fold(t1, t2, t3, slotB + e);
                  write_out4(ob + 5 * 84, t1, t2, t3); }
    if (w == 2) { BDX(14); sig_step(t1, t2, t3, dxl); chen_fold(t1, t2, t3, slotC + e);
                  write_out4(ob + 6 * 84, t1, t2, t3); }
    __syncthreads();
    if (w == 2) store_sig(slotB + e, t1, t2, t3);   // q3
    __syncthreads();
    // pg2 = q2 (x) exp(bdx h=12) (x) q3 -> stash to slotC
    if (w == 0) { BDX(12); sig_step(t1, t2, t3, dxl); chen_fold(t1, t2, t3, slotB + e);
                  write_out4(ob + 2 * 84, t1, t2, t3); store_sig(slotC + e, t1, t2, t3); }
    __syncthreads();
    // pg0 = pg1 (x) exp(bdx h=8) (x) pg2
    if (w == 0) {
        load_sig(slotA + e, t1, t2, t3);
        BDX(8); sig_step(t1, t2, t3, dxl);
        chen_fold(t1, t2, t3, slotC + e);
        write_out4(ob + 0 * 84, t1, t2, t3);
    }
#undef BDX
}

// Fallback: direct sequential scan per (b, piece) — only if ws is too small.
__global__ __launch_bounds__(64, 1)
void direct_kernel(const float* __restrict__ x, float* __restrict__ out) {
    const int pg = blockIdx.x % 15;
    const int b = blockIdx.x / 15;
    const int e = threadIdx.x;
    int lvl, p;
    if (pg == 0)      { lvl = 0; p = 0; }
    else if (pg < 3)  { lvl = 1; p = pg - 1; }
    else if (pg < 7)  { lvl = 2; p = pg - 3; }
    else              { lvl = 3; p = pg - 7; }
    const int L = 1024 >> lvl;
    const int t0 = p * L;
    const float4* xf = reinterpret_cast<const float4*>(x);
    const long base = (long)b * 65536;

    float4 prev = xf[base + (long)t0 * 64 + e];
    float s1[4], s2[16], s3[64];
    {
        float4 cur = xf[base + (long)(t0 + 1) * 64 + e];
        float dx[4] = {cur.x - prev.x, cur.y - prev.y, cur.z - prev.z, cur.w - prev.w};
        sig_init(s1, s2, s3, dx);
        prev = cur;
    }
    for (int i = 2; i < L; ++i) {
        float4 cur = xf[base + (long)(t0 + i) * 64 + e];
        float dx[4] = {cur.x - prev.x, cur.y - prev.y, cur.z - prev.z, cur.w - prev.w};
        prev = cur;
        sig_step(s1, s2, s3, dx);
    }
    write_out4(&out[(((long)(b * 64 + e)) * 15 + pg) * 84], s1, s2, s3);
}

extern "C" void kernel_launch(void* const* d_in, const int* in_sizes, int n_in,
                              void* d_out, int out_size, void* d_ws, size_t ws_size,
                              hipStream_t stream) {
    (void)in_sizes; (void)n_in; (void)out_size;
    const float* x = (const float*)d_in[0];
    float* out = (float*)d_out;

    const size_t h_elems = (size_t)64 * 16 * 84 * 64;   // hsig
    const size_t b_elems = (size_t)64 * 16 * 4 * 64;    // bdxh
    const size_t need = (h_elems + b_elems) * sizeof(float) + 64 * sizeof(unsigned int);

    if (ws_size >= need) {
        float* hsig = (float*)d_ws;
        float* bdxh = hsig + h_elems;
        unsigned int* cnt = (unsigned int*)(bdxh + b_elems);
        hipMemsetAsync(cnt, 0, 64 * sizeof(unsigned int), stream);
        fused_kernel<<<64 * 16, 256, 0, stream>>>(x, hsig, bdxh, cnt, out);
    } else {
        direct_kernel<<<64 * 15, 64, 0, stream>>>(x, out);
    }
}